// Round 1
// baseline (239.850 us; speedup 1.0000x reference)
//
#include <hip/hip_runtime.h>
#include <hip/hip_bf16.h>

#define HID   256
#define NP    100
#define KSZ   3
#define NPKS  (NP*KSZ)        // 300
#define K2PAD 384             // 3 * 128 (t*128 + c layout)
#define N1T   24              // 384/16 N-tiles of GEMM1
#define PC    104             // kT pitch in bf16 elems (c-dim)
#define KTROWS 258            // l = -1 .. 256
#define KT_ELEMS (KTROWS*PC + 80)   // 26912, guard for over-read, mult of 8
#define WS_PITCH 40
#define WS_ELEMS (112*WS_PITCH)     // 4480

using bf16x8 = __attribute__((ext_vector_type(8))) short;
using f32x4  = __attribute__((ext_vector_type(4))) float;

__device__ __forceinline__ short f2bf(float x) {
    __hip_bfloat16 h = __float2bfloat16(x);
    return __builtin_bit_cast(short, h);
}

// ---------- prep: W_lin -> bf16 B-fragment-ordered W2f, permuted bias ----------
__global__ void dyconv_prep(const float* __restrict__ W_lin,
                            const float* __restrict__ b_lin,
                            short* __restrict__ W2f,   // [8 kt][24 nt][64 lane][8] bf16
                            float* __restrict__ b2f) { // [384]
    int gid = blockIdx.x * blockDim.x + threadIdx.x;   // 0..12287
    int lane = gid & 63;
    int ent  = gid >> 6;            // kt*24 + nt, 0..191
    int kt = ent / N1T;
    int nt = ent % N1T;
    int n  = nt*16 + (lane & 15);   // K2 index of GEMM2 = t*128 + c
    int t  = n >> 7;
    int c  = n & 127;
    int k0 = kt*32 + ((lane >> 4) << 3);
    short vals[8];
#pragma unroll
    for (int j = 0; j < 8; ++j) {
        float v = (c < NP) ? W_lin[(k0 + j) * NPKS + c*KSZ + t] : 0.0f;
        vals[j] = f2bf(v);
    }
    *reinterpret_cast<bf16x8*>(&W2f[(size_t)gid * 8]) =
        *reinterpret_cast<bf16x8*>(vals);
    if (gid < K2PAD) {
        int tt = gid >> 7, cc = gid & 127;
        b2f[gid] = (cc < NP) ? b_lin[cc*KSZ + tt] : 0.0f;
    }
}

// ---------- main fused kernel: one block per batch ----------
__global__ __launch_bounds__(256)
void dyconv_main(const float* __restrict__ f, const float* __restrict__ k,
                 const short* __restrict__ W2f, const float* __restrict__ b2f,
                 const float* __restrict__ gamma, const float* __restrict__ beta,
                 float* __restrict__ out) {
    __shared__ short kT[KT_ELEMS];     // kT[l+1][c] = k[b][c][l], zero-padded
    __shared__ short wS[WS_ELEMS];     // w chunk [112][40] bf16 (+ LN overlay)
    float* lnbuf = reinterpret_cast<float*>(wS);

    const int b    = blockIdx.x;
    const int tid  = threadIdx.x;
    const int wave = tid >> 6;
    const int lane = tid & 63;
    const int lg   = lane >> 4;    // lane group 0..3
    const int li   = lane & 15;

    // zero kT (incl. guard) so every reachable LDS read is finite
    for (int i = tid; i < KT_ELEMS/8; i += 256)
        reinterpret_cast<int4*>(kT)[i] = make_int4(0,0,0,0);
    __syncthreads();

    // stage k[b] transposed into LDS as bf16
    const float* kb = k + (size_t)b * (NP*HID);
    for (int idx = tid; idx < NP*HID; idx += 256) {
        int c = idx >> 8, l = idx & 255;
        kT[(l+1)*PC + c] = f2bf(kb[idx]);
    }

    // preload GEMM1 A-fragments (f) once: wave w owns M-tiles {w, w+4} (<7)
    const float* fb = f + (size_t)b * (NP*HID);
    const int nmy = (wave < 3) ? 2 : 1;
    bf16x8 a1[2][8];
#pragma unroll
    for (int mi = 0; mi < 2; ++mi) {
        if (mi < nmy) {
            int mt = wave + 4*mi;
            int p  = mt*16 + li; if (p > NP-1) p = NP-1;   // clamp: pad rows read row 99
            const float* rowp = fb + (size_t)p * HID + lg*8;
#pragma unroll
            for (int kt = 0; kt < 8; ++kt) {
                float4 u = *reinterpret_cast<const float4*>(rowp + kt*32);
                float4 v = *reinterpret_cast<const float4*>(rowp + kt*32 + 4);
                short tmp[8] = {f2bf(u.x),f2bf(u.y),f2bf(u.z),f2bf(u.w),
                                f2bf(v.x),f2bf(v.y),f2bf(v.z),f2bf(v.w)};
                a1[mi][kt] = *reinterpret_cast<bf16x8*>(tmp);
            }
        }
    }

    f32x4 acc2[7][4];
#pragma unroll
    for (int mt = 0; mt < 7; ++mt)
#pragma unroll
        for (int j = 0; j < 4; ++j) acc2[mt][j] = (f32x4){0.f,0.f,0.f,0.f};

    __syncthreads();   // kT ready

    // ---- 12 chunks of 32 K2-columns: GEMM1 chunk -> LDS -> GEMM2 accumulate ----
    for (int kc = 0; kc < 12; ++kc) {
        f32x4 acc1[2][2];
#pragma unroll
        for (int mi = 0; mi < 2; ++mi)
#pragma unroll
            for (int n = 0; n < 2; ++n) acc1[mi][n] = (f32x4){0.f,0.f,0.f,0.f};

#pragma unroll
        for (int kt = 0; kt < 8; ++kt) {
            bf16x8 b1[2];
#pragma unroll
            for (int ntl = 0; ntl < 2; ++ntl) {
                int NT = kc*2 + ntl;
                b1[ntl] = *reinterpret_cast<const bf16x8*>(
                    &W2f[(((size_t)kt*N1T + NT)*64 + lane)*8]);
            }
#pragma unroll
            for (int mi = 0; mi < 2; ++mi) {
                if (mi < nmy) {
                    acc1[mi][0] = __builtin_amdgcn_mfma_f32_16x16x32_bf16(
                        a1[mi][kt], b1[0], acc1[mi][0], 0,0,0);
                    acc1[mi][1] = __builtin_amdgcn_mfma_f32_16x16x32_bf16(
                        a1[mi][kt], b1[1], acc1[mi][1], 0,0,0);
                }
            }
        }
        // bias + write w chunk to LDS (wS free: barrier at end of prev iter)
#pragma unroll
        for (int mi = 0; mi < 2; ++mi) {
            if (mi < nmy) {
                int mt = wave + 4*mi;
#pragma unroll
                for (int ntl = 0; ntl < 2; ++ntl) {
                    int col  = ntl*16 + li;
                    float bias = b2f[kc*32 + col];
#pragma unroll
                    for (int r = 0; r < 4; ++r) {
                        int row = mt*16 + lg*4 + r;
                        wS[row*WS_PITCH + col] = f2bf(acc1[mi][ntl][r] + bias);
                    }
                }
            }
        }
        __syncthreads();   // wS ready

        // GEMM2: wave owns l-tiles {4w..4w+3}, all 7 M-tiles
        bf16x8 a2[7];
#pragma unroll
        for (int mt = 0; mt < 7; ++mt)
            a2[mt] = *reinterpret_cast<const bf16x8*>(&wS[(mt*16 + li)*WS_PITCH + lg*8]);
        int k2 = kc*32 + lg*8;
        int t  = k2 >> 7;          // tap (uniform within 32-group: 32 | 128)
        int c  = k2 & 127;
#pragma unroll
        for (int j = 0; j < 4; ++j) {
            int l = (wave*4 + j)*16 + li;
            bf16x8 b2v = *reinterpret_cast<const bf16x8*>(&kT[(l + t)*PC + c]);
#pragma unroll
            for (int mt = 0; mt < 7; ++mt)
                acc2[mt][j] = __builtin_amdgcn_mfma_f32_16x16x32_bf16(
                    a2[mt], b2v, acc2[mt][j], 0,0,0);
        }
        __syncthreads();   // protect wS before next chunk's writes
    }

    // ---- LayerNorm over l (256) per row p ----
    float* psum  = lnbuf;            // [4 waves][112 rows][2]
    float* mrstd = lnbuf + 4*112*2;  // [112][2]
#pragma unroll
    for (int mt = 0; mt < 7; ++mt) {
#pragma unroll
        for (int r = 0; r < 4; ++r) {
            float s1 = 0.f, s2 = 0.f;
#pragma unroll
            for (int j = 0; j < 4; ++j) {
                float v = acc2[mt][j][r];
                s1 += v; s2 += v*v;
            }
#pragma unroll
            for (int m = 1; m < 16; m <<= 1) {
                s1 += __shfl_xor(s1, m, 64);
                s2 += __shfl_xor(s2, m, 64);
            }
            if (li == 0) {
                int p = mt*16 + lg*4 + r;
                psum[(wave*112 + p)*2 + 0] = s1;
                psum[(wave*112 + p)*2 + 1] = s2;
            }
        }
    }
    __syncthreads();
    if (tid < 112) {
        float S1 = 0.f, S2 = 0.f;
#pragma unroll
        for (int w2 = 0; w2 < 4; ++w2) {
            S1 += psum[(w2*112 + tid)*2 + 0];
            S2 += psum[(w2*112 + tid)*2 + 1];
        }
        float mean = S1 * (1.0f/HID);
        float var  = S2 * (1.0f/HID) - mean*mean;
        mrstd[tid*2 + 0] = mean;
        mrstd[tid*2 + 1] = rsqrtf(var + 1e-5f);
    }
    __syncthreads();

    float* ob = out + (size_t)b * (NP*HID);
#pragma unroll
    for (int j = 0; j < 4; ++j) {
        int l = (wave*4 + j)*16 + li;
        float g  = gamma[l];
        float be = beta[l];
#pragma unroll
        for (int mt = 0; mt < 7; ++mt) {
#pragma unroll
            for (int r = 0; r < 4; ++r) {
                int p = mt*16 + lg*4 + r;
                if (p < NP) {
                    float mean = mrstd[p*2], rstd = mrstd[p*2 + 1];
                    ob[p*HID + l] = (acc2[mt][j][r] - mean)*rstd*g + be;
                }
            }
        }
    }
}

extern "C" void kernel_launch(void* const* d_in, const int* in_sizes, int n_in,
                              void* d_out, int out_size, void* d_ws, size_t ws_size,
                              hipStream_t stream) {
    const float* f     = (const float*)d_in[0];
    const float* k     = (const float*)d_in[1];
    const float* W_lin = (const float*)d_in[2];
    const float* b_lin = (const float*)d_in[3];
    const float* gamma = (const float*)d_in[4];
    const float* beta  = (const float*)d_in[5];
    float* out = (float*)d_out;

    // workspace: W2f (8*24*64*8 bf16 = 196608 B) then b2f (384 f32)
    short* W2f = (short*)d_ws;
    float* b2f = (float*)((char*)d_ws + (size_t)8*N1T*64*8*2);

    const int B = in_sizes[0] / (NP*HID);   // 1024

    dyconv_prep<<<48, 256, 0, stream>>>(W_lin, b_lin, W2f, b2f);
    dyconv_main<<<B, 256, 0, stream>>>(f, k, W2f, b2f, gamma, beta, out);
}